// Round 9
// baseline (90.375 us; speedup 1.0000x reference)
//
#include <hip/hip_runtime.h>
#include <stdint.h>

#define NC13 507
#define NC26 2028
#define NC52 8112
#define NCAND 10647
#define KSEL 512
#define POOLCAP 768
#define POOLTGT 640
#define SUPW 17   // padded SUP row stride (17 coprime 32 -> conflict-free)
#define CMW 17    // padded class-mask stride
#define DECB 6    // decode blocks per image (4 s52 + 1 s26 + 1 s13)

// ---------------------------------------------------------------------------
// Key semantics (unchanged, verified absmax 0.0):
//   valid (xo>0):  bit63 | float_bits(xo)<<32 | (0x3FFF - n)
//   invalid     :  (0x3FFF - n)
// Descending key order == (conf desc, index asc) of the reference exactly.
// ---------------------------------------------------------------------------
__device__ __forceinline__ unsigned long long make_key(float xo, int n) {
    const unsigned long long low = (unsigned long long)(0x3FFFu - (unsigned)n);
    return (xo > 0.0f)
        ? ((1ull << 63) | ((unsigned long long)__float_as_uint(xo) << 32) | low)
        : low;
}

// ---------------------------------------------------------------------------
// Box decode (identical arithmetic to verified rounds: absmax 0.0).
// ---------------------------------------------------------------------------
__device__ __forceinline__ void decode_write(
    float* __restrict__ o, int w, int h, float ts,
    float tx, float ty, float tw, float th, float xo,
    float aw, float ah, int cls)
{
    const float sx   = 1.0f / (1.0f + expf(-tx));
    const float sy   = 1.0f / (1.0f + expf(-ty));
    const float conf = 1.0f / (1.0f + expf(-xo));
    const float cx = ((float)w + sx) * ts;
    const float cy = ((float)h + sy) * ts;
    const float bw = aw * expf(tw);
    const float bh = ah * expf(th);
    o[0] = cx - bw * 0.5f; o[1] = cy - bh * 0.5f;
    o[2] = cx + bw * 0.5f; o[3] = cy + bh * 0.5f;
    o[4] = conf; o[5] = (float)cls;
}

// float4 decode of 4 consecutive candidates (hw..hw+3); class loads in
// batches of 4 with 1-batch-ahead prefetch. Also emits the 4 sort keys.
__device__ __forceinline__ void decode4(
    const float* __restrict__ in, const float* __restrict__ anch,
    int b, int a, int hw, int HW, int Hdim, float ts, int base,
    float* __restrict__ boxesAll, unsigned long long* __restrict__ keys)
{
    const int HW4 = HW >> 2;
    const float4* p4 = reinterpret_cast<const float4*>(
        in + ((size_t)b * 255 + (size_t)a * 85) * HW + hw);

    const float4 txv = p4[0];
    const float4 tyv = p4[(size_t)HW4];
    const float4 twv = p4[(size_t)2 * HW4];
    const float4 thv = p4[(size_t)3 * HW4];
    const float4 xov = p4[(size_t)4 * HW4];

    float4 best = make_float4(-INFINITY, -INFINITY, -INFINITY, -INFINITY);
    int bx = 0, by = 0, bz = 0, bw4 = 0;

    float4 vb[4];
    #pragma unroll
    for (int j = 0; j < 4; ++j) vb[j] = p4[(size_t)(5 + j) * HW4];
    for (int cb = 0; cb < 20; ++cb) {
        float4 vn[4];
        if (cb < 19) {
            #pragma unroll
            for (int j = 0; j < 4; ++j) vn[j] = p4[(size_t)(9 + cb * 4 + j) * HW4];
        }
        #pragma unroll
        for (int j = 0; j < 4; ++j) {
            const int c = cb * 4 + j;          // strict > == first-max (jnp.argmax)
            if (vb[j].x > best.x) { best.x = vb[j].x; bx = c; }
            if (vb[j].y > best.y) { best.y = vb[j].y; by = c; }
            if (vb[j].z > best.z) { best.z = vb[j].z; bz = c; }
            if (vb[j].w > best.w) { best.w = vb[j].w; bw4 = c; }
        }
        #pragma unroll
        for (int j = 0; j < 4; ++j) vb[j] = vn[j];
    }

    // sort keys for the select kernel (reference candidate order n)
    unsigned long long* kb = keys + (size_t)b * NCAND;
    kb[base + (hw + 0) * 3 + a] = make_key(xov.x, base + (hw + 0) * 3 + a);
    kb[base + (hw + 1) * 3 + a] = make_key(xov.y, base + (hw + 1) * 3 + a);
    kb[base + (hw + 2) * 3 + a] = make_key(xov.z, base + (hw + 2) * 3 + a);
    kb[base + (hw + 3) * 3 + a] = make_key(xov.w, base + (hw + 3) * 3 + a);

    const float aw = anch[2 * a], ah = anch[2 * a + 1];
    const int i0 = base + a * HW + hw;
    float* o = boxesAll + ((size_t)b * NCAND + i0) * 6;
    {
        const int h = hw / Hdim, w = hw - h * Hdim;
        decode_write(o, w, h, ts, txv.x, tyv.x, twv.x, thv.x, xov.x, aw, ah, bx);
    }
    {
        const int h = (hw + 1) / Hdim, w = (hw + 1) - h * Hdim;
        decode_write(o + 6, w, h, ts, txv.y, tyv.y, twv.y, thv.y, xov.y, aw, ah, by);
    }
    {
        const int h = (hw + 2) / Hdim, w = (hw + 2) - h * Hdim;
        decode_write(o + 12, w, h, ts, txv.z, tyv.z, twv.z, thv.z, xov.z, aw, ah, bz);
    }
    {
        const int h = (hw + 3) / Hdim, w = (hw + 3) - h * Hdim;
        decode_write(o + 18, w, h, ts, txv.w, tyv.w, twv.w, thv.w, xov.w, aw, ah, bw4);
    }
}

// ---------------------------------------------------------------------------
// Kernel A: streaming decode of all candidates + key emission. Pure BW.
// grid (DECB, B), 512 threads.
// ---------------------------------------------------------------------------
__global__ __launch_bounds__(512, 2) void decode_kernel(
    const float* __restrict__ in13,
    const float* __restrict__ in26,
    const float* __restrict__ in52,
    const float* __restrict__ a13,
    const float* __restrict__ a26,
    const float* __restrict__ a52,
    float* __restrict__ boxesAll,
    unsigned long long* __restrict__ keys)
{
    const int role = blockIdx.x;
    const int b = blockIdx.y;
    const int tid = threadIdx.x;

    if (role < 4) {                      // s52: 2028 float4-groups over 4 blocks
        const int idx4 = role * 512 + tid;
        if (idx4 < 3 * 676) {
            const int a = idx4 / 676, g = idx4 - a * 676;
            decode4(in52, a52, b, a, g * 4, 2704, 52, 8.f, NC13 + NC26, boxesAll, keys);
        }
    } else if (role == 4) {              // s26: 507 float4-groups, 1 block
        if (tid < 3 * 169) {
            const int a = tid / 169, g = tid - a * 169;
            decode4(in26, a26, b, a, g * 4, 676, 26, 16.f, NC13, boxesAll, keys);
        }
    } else {                             // s13: 507 scalar, 1 block
        if (tid < NC13) {
            const int HW = 169;
            const int a = tid / HW, hw = tid - a * HW;
            const int h = hw / 13, w = hw - h * 13;
            const float* p = in13 + ((size_t)b * 255 + (size_t)a * 85) * HW + hw;
            const float tx = p[0];
            const float ty = p[(size_t)HW];
            const float tw = p[(size_t)2 * HW];
            const float th = p[(size_t)3 * HW];
            const float xo = p[(size_t)4 * HW];
            float best = -INFINITY; int bi = 0;
            float vb[4];
            #pragma unroll
            for (int j = 0; j < 4; ++j) vb[j] = p[(size_t)(5 + j) * HW];
            for (int cb = 0; cb < 20; ++cb) {
                float vn[4];
                if (cb < 19) {
                    #pragma unroll
                    for (int j = 0; j < 4; ++j) vn[j] = p[(size_t)(9 + cb * 4 + j) * HW];
                }
                #pragma unroll
                for (int j = 0; j < 4; ++j) {
                    const int c = cb * 4 + j;
                    if (vb[j] > best) { best = vb[j]; bi = c; }
                }
                #pragma unroll
                for (int j = 0; j < 4; ++j) vb[j] = vn[j];
            }
            const int n = hw * 3 + a;                 // base 0
            keys[(size_t)b * NCAND + n] = make_key(xo, n);
            const int i = a * HW + hw;
            decode_write(boxesAll + ((size_t)b * NCAND + i) * 6, w, h, 32.f,
                         tx, ty, tw, th, xo, a13[2 * a], a13[2 * a + 1], bi);
        }
    }
}

// ---------------------------------------------------------------------------
// Kernel B: per-image select (radix top-512 on compact keys) + NMS, fused.
// One block per image, 512 threads. Select results live in LDS only.
// ---------------------------------------------------------------------------
struct SelS {
    unsigned int hist[4096];
    unsigned long long pool[POOLCAP];
    unsigned int cnt;
    unsigned long long prefix;
    unsigned long long tmin;
    int krem, shift, brk, include;
};
struct NmsS {
    float X1[KSEL], Y1[KSEL], X2[KSEL], Y2[KSEL], AR[KSEL];
    int CLS[KSEL];
    unsigned int CM[80 * CMW];
    unsigned int SUP[KSEL * SUPW];
    unsigned int KEEP[16];
};

__global__ __launch_bounds__(512) void selnms_kernel(
    const unsigned long long* __restrict__ keys,
    const float* __restrict__ boxesAll,
    float* __restrict__ out)
{
    constexpr size_t USZ = sizeof(SelS) > sizeof(NmsS) ? sizeof(SelS) : sizeof(NmsS);
    __shared__ __align__(16) char smem[USZ];
    __shared__ int selidxL[KSEL];
    __shared__ int shVtot;

    const int b = blockIdx.x;
    const int tid = threadIdx.x;
    const unsigned long long* kb = keys + (size_t)b * NCAND;

    // ======================= PHASE 1: SELECT =======================
    {
        SelS& S = *reinterpret_cast<SelS*>(smem);
        if (tid == 0) { S.cnt = 0; S.prefix = 0; S.krem = KSEL; S.shift = 52; S.brk = 0; S.include = 0; }
        __syncthreads();

        bool first = true;
        while (true) {
            const int shift = S.shift;
            const unsigned long long prefix = S.prefix;
            const int krem = S.krem;
            const int include = S.include;
            __syncthreads();
            for (int i = tid; i < 4096; i += 512) S.hist[i] = 0;
            __syncthreads();
            for (int i = tid; i < NCAND; i += 512) {
                const unsigned long long k = kb[i];
                const bool part = include || ((k >> 63) != 0ull);
                const bool ok = part &&
                    ((shift == 52) || ((k >> (shift + 12)) == prefix));
                if (ok) atomicAdd(&S.hist[(unsigned)((k >> shift) & 0xFFFull)], 1u);
            }
            __syncthreads();

            if (first) {
                // V = total valid = lane-0 suffix total of this histogram
                if (tid < 64) {
                    unsigned int s = 0;
                    for (int q = 0; q < 64; ++q) s += S.hist[tid * 64 + q];
                    unsigned int suf = s;
                    for (int off = 1; off < 64; off <<= 1) {
                        const unsigned int v = __shfl_down(suf, off);
                        if (tid + off < 64) suf += v;
                    }
                    if (tid == 0) shVtot = (int)suf;
                }
                __syncthreads();
                if (tid == 0 && shVtot < KSEL) {   // degenerate: admit invalid keys
                    S.hist[0] += (unsigned)(NCAND - shVtot);
                    S.include = 1;
                }
                __syncthreads();
                first = false;
            }

            if (tid < 64) {
                unsigned int s = 0;
                for (int q = 0; q < 64; ++q) s += S.hist[tid * 64 + q];
                unsigned int suf = s;
                for (int off = 1; off < 64; off <<= 1) {
                    const unsigned int v = __shfl_down(suf, off);
                    if (tid + off < 64) suf += v;
                }
                const unsigned long long ball = __ballot(suf >= (unsigned)krem);
                const int lstar = 63 - __clzll(ball);
                const unsigned int base = (lstar < 63) ? __shfl(suf, lstar + 1) : 0u;
                const unsigned int wv = S.hist[lstar * 64 + (63 - tid)];
                unsigned int pv = wv;
                for (int off = 1; off < 64; off <<= 1) {
                    const unsigned int v = __shfl_up(pv, off);
                    if (tid >= (unsigned)off) pv += v;
                }
                const unsigned long long b2 = __ballot(base + pv >= (unsigned)krem);
                const int mstar = __ffsll(b2) - 1;
                const unsigned int pvm = __shfl(pv, mstar);
                const unsigned int wvm = __shfl(wv, mstar);
                if (tid == 0) {
                    const int dstar = lstar * 64 + (63 - mstar);
                    const unsigned long long np = (prefix << 12) | (unsigned long long)dstar;
                    const int Albl = (int)(base + pvm - wvm);
                    const int Cpool = (KSEL - krem) + Albl + (int)wvm;
                    S.prefix = np;
                    S.krem = krem - Albl;
                    if (Cpool <= POOLTGT || shift == 4) {
                        S.brk = 1;
                        S.tmin = np << shift;
                    } else {
                        S.shift = shift - 12;
                    }
                }
            }
            __syncthreads();
            if (S.brk) break;
        }
        const unsigned long long tmin = S.tmin;

        for (int i = tid; i < NCAND; i += 512) {
            const unsigned long long k = kb[i];
            if (k >= tmin) {
                const unsigned int p = atomicAdd(&S.cnt, 1u);
                if (p < POOLCAP) S.pool[p] = k;
            }
        }
        __syncthreads();
        const int C = ((int)S.cnt < POOLCAP) ? (int)S.cnt : POOLCAP;

        for (int p = tid; p < C; p += 512) {
            const unsigned long long k = S.pool[p];
            int r = 0;
            for (int j = 0; j < C; ++j) r += (S.pool[j] > k) ? 1 : 0;
            if (r < KSEL) selidxL[r] = 0x3FFF - (int)(k & 0x3FFFull);
        }
        __syncthreads();
    }

    // ======================= PHASE 2: NMS =======================
    NmsS& M = *reinterpret_cast<NmsS*>(smem);
    const int V = (shVtot < KSEL) ? shVtot : KSEL;   // valid is a prefix

    const int n = selidxL[tid];
    int base, HW;
    if (n < NC13)             { base = 0;           HW = 169; }
    else if (n < NC13 + NC26) { base = NC13;        HW = 676; }
    else                      { base = NC13 + NC26; HW = 2704; }
    const int within = n - base;
    const int hw = within / 3, a = within - 3 * hw;
    const int i = base + a * HW + hw;
    const float* src = boxesAll + ((size_t)b * NCAND + i) * 6;
    const float x1 = src[0], y1 = src[1], x2 = src[2], y2 = src[3];
    const float conf = src[4], clsf = src[5];
    const float ar = (x2 - x1) * (y2 - y1);
    const int ci = (int)clsf;
    M.X1[tid] = x1; M.Y1[tid] = y1; M.X2[tid] = x2; M.Y2[tid] = y2;
    M.AR[tid] = ar; M.CLS[tid] = ci;
    for (int q = tid; q < 80 * CMW; q += KSEL) M.CM[q] = 0;
    __syncthreads();

    atomicOr(&M.CM[ci * CMW + (tid >> 5)], 1u << (tid & 31));
    __syncthreads();

    for (int wj = 0; wj < 16; ++wj) {
        unsigned int m = M.CM[ci * CMW + wj];
        unsigned int bits = 0;
        while (m) {
            const int bit = __ffs(m) - 1;
            m &= m - 1;
            const int j = wj * 32 + bit;
            const float iw = fminf(x2, M.X2[j]) - fmaxf(x1, M.X1[j]);
            const float ih = fminf(y2, M.Y2[j]) - fmaxf(y1, M.Y1[j]);
            if (iw > 0.0f && ih > 0.0f) {
                const float inter = iw * ih;
                if (inter > 0.3f * (ar + M.AR[j] - inter + 1e-9f))
                    bits |= (1u << bit);
            }
        }
        M.SUP[tid * SUPW + wj] = bits;
    }
    __syncthreads();

    if (tid < 64) {
        unsigned int keepw = 0;       // lanes 0..15 hold the 512-bit keep mask
        unsigned int buf[16];
        #pragma unroll
        for (int r = 0; r < 16; ++r)
            buf[r] = (tid < 16) ? M.SUP[r * SUPW + tid] : 0u;
        for (int g = 0; g < 32; ++g) {
            unsigned int nbuf[16] = {0};
            if (g < 31) {
                #pragma unroll
                for (int r = 0; r < 16; ++r)
                    nbuf[r] = (tid < 16) ? M.SUP[((g + 1) * 16 + r) * SUPW + tid] : 0u;
            }
            #pragma unroll
            for (int r = 0; r < 16; ++r) {
                const int ii = g * 16 + r;
                const bool anysup = __any((keepw & buf[r]) != 0u);
                const bool ki = (ii < V) && !anysup;
                if (ki && tid == (ii >> 5)) keepw |= (1u << (ii & 31));
            }
            #pragma unroll
            for (int r = 0; r < 16; ++r) buf[r] = nbuf[r];
        }
        if (tid < 16) M.KEEP[tid] = keepw;
    }
    __syncthreads();

    const float kf = ((M.KEEP[tid >> 5] >> (tid & 31)) & 1u) ? 1.0f : 0.0f;
    float* dst = out + ((size_t)b * KSEL + tid) * 7;
    dst[0] = x1; dst[1] = y1; dst[2] = x2;
    dst[3] = y2; dst[4] = conf; dst[5] = clsf;
    dst[6] = kf;
}

// ---------------------------------------------------------------------------
extern "C" void kernel_launch(void* const* d_in, const int* in_sizes, int n_in,
                              void* d_out, int out_size, void* d_ws, size_t ws_size,
                              hipStream_t stream)
{
    (void)n_in; (void)out_size; (void)ws_size;
    const float* in13 = (const float*)d_in[0];
    const float* in26 = (const float*)d_in[1];
    const float* in52 = (const float*)d_in[2];
    const float* a13  = (const float*)d_in[3];
    const float* a26  = (const float*)d_in[4];
    const float* a52  = (const float*)d_in[5];
    float* out = (float*)d_out;
    const int B = in_sizes[0] / (255 * 169);

    char* w = (char*)d_ws;
    unsigned long long* keys = (unsigned long long*)w;
    w += ((size_t)B * NCAND * sizeof(unsigned long long) + 255) & ~(size_t)255;
    float* boxesAll = (float*)w;
    w += ((size_t)B * NCAND * 6 * sizeof(float) + 255) & ~(size_t)255;

    decode_kernel<<<dim3(DECB, B), 512, 0, stream>>>(
        in13, in26, in52, a13, a26, a52, boxesAll, keys);
    selnms_kernel<<<dim3(B), 512, 0, stream>>>(keys, boxesAll, out);
}

// Round 10
// 81.864 us; speedup vs baseline: 1.1040x; 1.1040x over previous
//
#include <hip/hip_runtime.h>
#include <stdint.h>

#define NC13 507
#define NC26 2028
#define NC52 8112
#define NCAND 10647
#define KSEL 512
#define POOLCAP 768
#define POOLTGT 640
#define SUPW 17   // padded SUP row stride (17 coprime 32 -> conflict-free)
#define CMW 17    // padded class-mask stride
#define DECB 6    // decode blocks per image (4 s52 + 1 s26 + 1 s13)
#define HBINS 4096

// ---------------------------------------------------------------------------
// Key semantics (verified absmax 0.0 across rounds):
//   valid (xo>0):  bit63 | float_bits(xo)<<32 | (0x3FFF - n)
//   invalid     :  (0x3FFF - n)        (radix digit at shift 52 == 0)
// Descending key order == (conf desc, index asc) of the reference exactly.
// ---------------------------------------------------------------------------
__device__ __forceinline__ unsigned long long make_key(float xo, int n) {
    const unsigned long long low = (unsigned long long)(0x3FFFu - (unsigned)n);
    return (xo > 0.0f)
        ? ((1ull << 63) | ((unsigned long long)__float_as_uint(xo) << 32) | low)
        : low;
}

// ---------------------------------------------------------------------------
// Box decode (identical arithmetic to verified rounds: absmax 0.0).
// ---------------------------------------------------------------------------
__device__ __forceinline__ void decode_write(
    float* __restrict__ o, int w, int h, float ts,
    float tx, float ty, float tw, float th, float xo,
    float aw, float ah, int cls)
{
    const float sx   = 1.0f / (1.0f + expf(-tx));
    const float sy   = 1.0f / (1.0f + expf(-ty));
    const float conf = 1.0f / (1.0f + expf(-xo));
    const float cx = ((float)w + sx) * ts;
    const float cy = ((float)h + sy) * ts;
    const float bw = aw * expf(tw);
    const float bh = ah * expf(th);
    o[0] = cx - bw * 0.5f; o[1] = cy - bh * 0.5f;
    o[2] = cx + bw * 0.5f; o[3] = cy + bh * 0.5f;
    o[4] = conf; o[5] = (float)cls;
}

__device__ __forceinline__ void emit_key(
    unsigned long long* __restrict__ kb, unsigned int* __restrict__ lh,
    float xo, int n)
{
    const unsigned long long k = make_key(xo, n);
    kb[n] = k;
    atomicAdd(&lh[(unsigned)((k >> 52) & 0xFFFull)], 1u);
}

// float4 decode of 4 consecutive candidates (hw..hw+3); class loads in
// batches of 4 with 1-batch-ahead prefetch. Emits keys + LDS histogram.
__device__ __forceinline__ void decode4(
    const float* __restrict__ in, const float* __restrict__ anch,
    int b, int a, int hw, int HW, int Hdim, float ts, int base,
    float* __restrict__ boxesAll, unsigned long long* __restrict__ keys,
    unsigned int* __restrict__ lh)
{
    const int HW4 = HW >> 2;
    const float4* p4 = reinterpret_cast<const float4*>(
        in + ((size_t)b * 255 + (size_t)a * 85) * HW + hw);

    const float4 txv = p4[0];
    const float4 tyv = p4[(size_t)HW4];
    const float4 twv = p4[(size_t)2 * HW4];
    const float4 thv = p4[(size_t)3 * HW4];
    const float4 xov = p4[(size_t)4 * HW4];

    float4 best = make_float4(-INFINITY, -INFINITY, -INFINITY, -INFINITY);
    int bx = 0, by = 0, bz = 0, bw4 = 0;

    float4 vb[4];
    #pragma unroll
    for (int j = 0; j < 4; ++j) vb[j] = p4[(size_t)(5 + j) * HW4];
    for (int cb = 0; cb < 20; ++cb) {
        float4 vn[4];
        if (cb < 19) {
            #pragma unroll
            for (int j = 0; j < 4; ++j) vn[j] = p4[(size_t)(9 + cb * 4 + j) * HW4];
        }
        #pragma unroll
        for (int j = 0; j < 4; ++j) {
            const int c = cb * 4 + j;          // strict > == first-max (jnp.argmax)
            if (vb[j].x > best.x) { best.x = vb[j].x; bx = c; }
            if (vb[j].y > best.y) { best.y = vb[j].y; by = c; }
            if (vb[j].z > best.z) { best.z = vb[j].z; bz = c; }
            if (vb[j].w > best.w) { best.w = vb[j].w; bw4 = c; }
        }
        #pragma unroll
        for (int j = 0; j < 4; ++j) vb[j] = vn[j];
    }

    unsigned long long* kb = keys + (size_t)b * NCAND;
    emit_key(kb, lh, xov.x, base + (hw + 0) * 3 + a);
    emit_key(kb, lh, xov.y, base + (hw + 1) * 3 + a);
    emit_key(kb, lh, xov.z, base + (hw + 2) * 3 + a);
    emit_key(kb, lh, xov.w, base + (hw + 3) * 3 + a);

    const float aw = anch[2 * a], ah = anch[2 * a + 1];
    const int i0 = base + a * HW + hw;
    float* o = boxesAll + ((size_t)b * NCAND + i0) * 6;
    {
        const int h = hw / Hdim, w = hw - h * Hdim;
        decode_write(o, w, h, ts, txv.x, tyv.x, twv.x, thv.x, xov.x, aw, ah, bx);
    }
    {
        const int h = (hw + 1) / Hdim, w = (hw + 1) - h * Hdim;
        decode_write(o + 6, w, h, ts, txv.y, tyv.y, twv.y, thv.y, xov.y, aw, ah, by);
    }
    {
        const int h = (hw + 2) / Hdim, w = (hw + 2) - h * Hdim;
        decode_write(o + 12, w, h, ts, txv.z, tyv.z, twv.z, thv.z, xov.z, aw, ah, bz);
    }
    {
        const int h = (hw + 3) / Hdim, w = (hw + 3) - h * Hdim;
        decode_write(o + 18, w, h, ts, txv.w, tyv.w, twv.w, thv.w, xov.w, aw, ah, bw4);
    }
}

// ---------------------------------------------------------------------------
// Kernel A: streaming decode + keys + per-image radix histogram.
// grid (DECB, B), 512 threads. `hist` must be pre-zeroed (hipMemsetAsync).
// ---------------------------------------------------------------------------
__global__ __launch_bounds__(512, 2) void decode_kernel(
    const float* __restrict__ in13,
    const float* __restrict__ in26,
    const float* __restrict__ in52,
    const float* __restrict__ a13,
    const float* __restrict__ a26,
    const float* __restrict__ a52,
    float* __restrict__ boxesAll,
    unsigned long long* __restrict__ keys,
    unsigned int* __restrict__ hist)
{
    __shared__ unsigned int lh[HBINS];
    const int role = blockIdx.x;
    const int b = blockIdx.y;
    const int tid = threadIdx.x;

    for (int i = tid; i < HBINS; i += 512) lh[i] = 0;
    __syncthreads();

    if (role < 4) {                      // s52: 2028 float4-groups over 4 blocks
        const int idx4 = role * 512 + tid;
        if (idx4 < 3 * 676) {
            const int a = idx4 / 676, g = idx4 - a * 676;
            decode4(in52, a52, b, a, g * 4, 2704, 52, 8.f, NC13 + NC26,
                    boxesAll, keys, lh);
        }
    } else if (role == 4) {              // s26: 507 float4-groups, 1 block
        if (tid < 3 * 169) {
            const int a = tid / 169, g = tid - a * 169;
            decode4(in26, a26, b, a, g * 4, 676, 26, 16.f, NC13,
                    boxesAll, keys, lh);
        }
    } else {                             // s13: 507 scalar, 1 block
        if (tid < NC13) {
            const int HW = 169;
            const int a = tid / HW, hw = tid - a * HW;
            const int h = hw / 13, w = hw - h * 13;
            const float* p = in13 + ((size_t)b * 255 + (size_t)a * 85) * HW + hw;
            const float tx = p[0];
            const float ty = p[(size_t)HW];
            const float tw = p[(size_t)2 * HW];
            const float th = p[(size_t)3 * HW];
            const float xo = p[(size_t)4 * HW];
            float best = -INFINITY; int bi = 0;
            float vb[4];
            #pragma unroll
            for (int j = 0; j < 4; ++j) vb[j] = p[(size_t)(5 + j) * HW];
            for (int cb = 0; cb < 20; ++cb) {
                float vn[4];
                if (cb < 19) {
                    #pragma unroll
                    for (int j = 0; j < 4; ++j) vn[j] = p[(size_t)(9 + cb * 4 + j) * HW];
                }
                #pragma unroll
                for (int j = 0; j < 4; ++j) {
                    const int c = cb * 4 + j;
                    if (vb[j] > best) { best = vb[j]; bi = c; }
                }
                #pragma unroll
                for (int j = 0; j < 4; ++j) vb[j] = vn[j];
            }
            const int n = hw * 3 + a;                 // base 0
            emit_key(keys + (size_t)b * NCAND, lh, xo, n);
            const int i = a * HW + hw;
            decode_write(boxesAll + ((size_t)b * NCAND + i) * 6, w, h, 32.f,
                         tx, ty, tw, th, xo, a13[2 * a], a13[2 * a + 1], bi);
        }
    }

    __syncthreads();
    unsigned int* hb = hist + (size_t)b * HBINS;
    for (int i = tid; i < HBINS; i += 512) {
        const unsigned int v = lh[i];
        if (v) atomicAdd(&hb[i], v);
    }
}

// ---------------------------------------------------------------------------
// Kernel B: per-image select (from precomputed histogram) + NMS.
// One block per image, 1024 threads.
// ---------------------------------------------------------------------------
struct SelS {
    unsigned int hist[HBINS];
    unsigned long long pool[POOLCAP];
};
struct NmsS {
    float X1[KSEL], Y1[KSEL], X2[KSEL], Y2[KSEL], AR[KSEL], CF[KSEL];
    int CLS[KSEL];
    unsigned int CM[80 * CMW];
    unsigned int SUP[KSEL * SUPW];
    unsigned int KEEP[16];
};

__global__ __launch_bounds__(1024) void selnms_kernel(
    const unsigned long long* __restrict__ keys,
    const unsigned int* __restrict__ hist,
    const float* __restrict__ boxesAll,
    float* __restrict__ out)
{
    constexpr size_t USZ = sizeof(SelS) > sizeof(NmsS) ? sizeof(SelS) : sizeof(NmsS);
    __shared__ __align__(16) char smem[USZ];
    __shared__ int selidxL[KSEL];
    __shared__ unsigned long long sh_prefix, sh_tmin;
    __shared__ int sh_krem, sh_shift, sh_brk, sh_V;
    __shared__ unsigned int sh_cnt;

    const int b = blockIdx.x;
    const int tid = threadIdx.x;
    const unsigned long long* kb = keys + (size_t)b * NCAND;
    SelS& S = *reinterpret_cast<SelS*>(smem);

    // ---- load precomputed histogram (16 KB, 4 coalesced iterations) ----
    {
        const unsigned int* gh = hist + (size_t)b * HBINS;
        for (int i = tid; i < HBINS; i += 1024) S.hist[i] = gh[i];
    }
    if (tid == 0) { sh_cnt = 0; sh_prefix = 0; sh_krem = KSEL; sh_shift = 52; sh_brk = 0; }
    __syncthreads();

    // ---- radix scan (usually terminates on the precomputed histogram) ----
    bool first = true;
    while (true) {
        const int shift = sh_shift;
        const unsigned long long prefix = sh_prefix;
        const int krem = sh_krem;
        if (tid < 64) {
            unsigned int s = 0;
            for (int q = 0; q < 64; ++q) s += S.hist[tid * 64 + q];
            unsigned int suf = s;
            for (int off = 1; off < 64; off <<= 1) {
                const unsigned int v = __shfl_down(suf, off);
                if (tid + off < 64) suf += v;
            }
            if (first) {   // V = #valid = bins >= 2048 = suffix at lane 32
                const unsigned int Vv = __shfl(suf, 32);
                if (tid == 0) sh_V = (int)Vv;
            }
            const unsigned long long ball = __ballot(suf >= (unsigned)krem);
            const int lstar = 63 - __clzll(ball);
            const unsigned int base = (lstar < 63) ? __shfl(suf, lstar + 1) : 0u;
            const unsigned int wv = S.hist[lstar * 64 + (63 - tid)];
            unsigned int pv = wv;
            for (int off = 1; off < 64; off <<= 1) {
                const unsigned int v = __shfl_up(pv, off);
                if (tid >= (unsigned)off) pv += v;
            }
            const unsigned long long b2 = __ballot(base + pv >= (unsigned)krem);
            const int mstar = __ffsll(b2) - 1;
            const unsigned int pvm = __shfl(pv, mstar);
            const unsigned int wvm = __shfl(wv, mstar);
            if (tid == 0) {
                const int dstar = lstar * 64 + (63 - mstar);
                const unsigned long long np = (prefix << 12) | (unsigned long long)dstar;
                const int Albl = (int)(base + pvm - wvm);
                const int Cpool = (KSEL - krem) + Albl + (int)wvm;
                sh_prefix = np;
                sh_krem = krem - Albl;
                if (Cpool <= POOLTGT || shift == 4) {
                    sh_brk = 1;
                    sh_tmin = np << shift;
                } else {
                    sh_shift = shift - 12;
                }
            }
        }
        __syncthreads();
        first = false;
        if (sh_brk) break;

        // rare exact-refinement path: rebuild histogram at finer shift
        const int nshift = sh_shift;
        const unsigned long long nprefix = sh_prefix;
        for (int i = tid; i < HBINS; i += 1024) S.hist[i] = 0;
        __syncthreads();
        for (int i = tid; i < NCAND; i += 1024) {
            const unsigned long long k = kb[i];
            if ((k >> (nshift + 12)) == nprefix)
                atomicAdd(&S.hist[(unsigned)((k >> nshift) & 0xFFFull)], 1u);
        }
        __syncthreads();
    }
    const unsigned long long tmin = sh_tmin;

    // ---- gather pool (single 11-iteration pass) ----
    for (int i = tid; i < NCAND; i += 1024) {
        const unsigned long long k = kb[i];
        if (k >= tmin) {
            const unsigned int p = atomicAdd(&sh_cnt, 1u);
            if (p < POOLCAP) S.pool[p] = k;
        }
    }
    __syncthreads();
    const int C = ((int)sh_cnt < POOLCAP) ? (int)sh_cnt : POOLCAP;

    // ---- exact rank (keys globally distinct) ----
    for (int p = tid; p < C; p += 1024) {
        const unsigned long long k = S.pool[p];
        int r = 0;
        for (int j = 0; j < C; ++j) r += (S.pool[j] > k) ? 1 : 0;
        if (r < KSEL) selidxL[r] = 0x3FFF - (int)(k & 0x3FFFull);
    }
    const int V = (sh_V < KSEL) ? sh_V : KSEL;   // valid is a prefix of ranks
    __syncthreads();

    // ======================= NMS phase =======================
    NmsS& M = *reinterpret_cast<NmsS*>(smem);
    const int t5 = tid & 511;
    const int half = tid >> 9;

    const int n = selidxL[t5];
    int base, HW;
    if (n < NC13)             { base = 0;           HW = 169; }
    else if (n < NC13 + NC26) { base = NC13;        HW = 676; }
    else                      { base = NC13 + NC26; HW = 2704; }
    const int within = n - base;
    const int hw = within / 3, a = within - 3 * hw;
    const int i = base + a * HW + hw;

    if (half == 0) {
        const float* src = boxesAll + ((size_t)b * NCAND + i) * 6;
        const float x1 = src[0], y1 = src[1], x2 = src[2], y2 = src[3];
        M.X1[t5] = x1; M.Y1[t5] = y1; M.X2[t5] = x2; M.Y2[t5] = y2;
        M.AR[t5] = (x2 - x1) * (y2 - y1);
        M.CF[t5] = src[4];
        M.CLS[t5] = (int)src[5];
    }
    for (int q = tid; q < 80 * CMW; q += 1024) M.CM[q] = 0;
    __syncthreads();

    const float x1 = M.X1[t5], y1 = M.Y1[t5], x2 = M.X2[t5], y2 = M.Y2[t5];
    const float ar = M.AR[t5];
    const int ci = M.CLS[t5];
    if (half == 0) atomicOr(&M.CM[ci * CMW + (t5 >> 5)], 1u << (t5 & 31));
    __syncthreads();

    // suppress matrix: box t5, wj range split across the two halves
    for (int wj = half * 8; wj < half * 8 + 8; ++wj) {
        unsigned int m = M.CM[ci * CMW + wj];
        unsigned int bits = 0;
        while (m) {
            const int bit = __ffs(m) - 1;
            m &= m - 1;
            const int j = wj * 32 + bit;
            const float iw = fminf(x2, M.X2[j]) - fmaxf(x1, M.X1[j]);
            const float ih = fminf(y2, M.Y2[j]) - fmaxf(y1, M.Y1[j]);
            if (iw > 0.0f && ih > 0.0f) {
                const float inter = iw * ih;
                if (inter > 0.3f * (ar + M.AR[j] - inter + 1e-9f))
                    bits |= (1u << bit);
            }
        }
        M.SUP[t5 * SUPW + wj] = bits;
    }
    __syncthreads();

    // sequential greedy scan (exact lax.scan semantics), wave 0 only
    if (tid < 64) {
        unsigned int keepw = 0;       // lanes 0..15 hold the 512-bit keep mask
        unsigned int buf[16];
        #pragma unroll
        for (int r = 0; r < 16; ++r)
            buf[r] = (tid < 16) ? M.SUP[r * SUPW + tid] : 0u;
        for (int g = 0; g < 32; ++g) {
            unsigned int nbuf[16] = {0};
            if (g < 31) {
                #pragma unroll
                for (int r = 0; r < 16; ++r)
                    nbuf[r] = (tid < 16) ? M.SUP[((g + 1) * 16 + r) * SUPW + tid] : 0u;
            }
            #pragma unroll
            for (int r = 0; r < 16; ++r) {
                const int ii = g * 16 + r;
                const bool anysup = __any((keepw & buf[r]) != 0u);
                const bool ki = (ii < V) && !anysup;
                if (ki && tid == (ii >> 5)) keepw |= (1u << (ii & 31));
            }
            #pragma unroll
            for (int r = 0; r < 16; ++r) buf[r] = nbuf[r];
        }
        if (tid < 16) M.KEEP[tid] = keepw;
    }
    __syncthreads();

    if (tid < 512) {
        const float kf = ((M.KEEP[t5 >> 5] >> (t5 & 31)) & 1u) ? 1.0f : 0.0f;
        float* dst = out + ((size_t)b * KSEL + t5) * 7;
        dst[0] = x1; dst[1] = y1; dst[2] = x2; dst[3] = y2;
        dst[4] = M.CF[t5]; dst[5] = (float)ci; dst[6] = kf;
    }
}

// ---------------------------------------------------------------------------
extern "C" void kernel_launch(void* const* d_in, const int* in_sizes, int n_in,
                              void* d_out, int out_size, void* d_ws, size_t ws_size,
                              hipStream_t stream)
{
    (void)n_in; (void)out_size; (void)ws_size;
    const float* in13 = (const float*)d_in[0];
    const float* in26 = (const float*)d_in[1];
    const float* in52 = (const float*)d_in[2];
    const float* a13  = (const float*)d_in[3];
    const float* a26  = (const float*)d_in[4];
    const float* a52  = (const float*)d_in[5];
    float* out = (float*)d_out;
    const int B = in_sizes[0] / (255 * 169);

    char* w = (char*)d_ws;
    unsigned long long* keys = (unsigned long long*)w;
    w += ((size_t)B * NCAND * sizeof(unsigned long long) + 255) & ~(size_t)255;
    float* boxesAll = (float*)w;
    w += ((size_t)B * NCAND * 6 * sizeof(float) + 255) & ~(size_t)255;
    unsigned int* hist = (unsigned int*)w;
    w += ((size_t)B * HBINS * sizeof(unsigned int) + 255) & ~(size_t)255;

    hipMemsetAsync(hist, 0, (size_t)B * HBINS * sizeof(unsigned int), stream);
    decode_kernel<<<dim3(DECB, B), 512, 0, stream>>>(
        in13, in26, in52, a13, a26, a52, boxesAll, keys, hist);
    selnms_kernel<<<dim3(B), 1024, 0, stream>>>(keys, hist, boxesAll, out);
}